// Round 1
// baseline (64.898 us; speedup 1.0000x reference)
//
#include <hip/hip_runtime.h>

// FlexTree: y = g(h @ w_root), h[c] = g(sum_d X[n, leaf_idx[c,d]] * W_child[c,d]),
// g(x) = exp(-((x-a)/b)^2).  N=1048576, F=64, C=8, D=4.  Memory-bound: 256 MB read.

#define TILE 256
#define PAD  65   // 65 mod 32 == 1 -> LDS bank = (t + f) mod 32 -> 2-way (free)

__global__ __launch_bounds__(256) void flextree_kernel(
    const float* __restrict__ X,
    const int*   __restrict__ leaf_idx,   // [8*4]
    const float* __restrict__ Wc,         // [8*4]
    const float* __restrict__ wr,         // [8]
    const float* __restrict__ pa,
    const float* __restrict__ pb,
    float* __restrict__ out,
    int n)
{
    __shared__ float tile[TILE * PAD];
    const int t    = threadIdx.x;
    const int row0 = blockIdx.x * TILE;
    const int rows = min(TILE, n - row0);

    // ---- stage `rows` rows (64 f32 each) into LDS, coalesced float4 loads ----
    const float4* Xv = reinterpret_cast<const float4*>(X + (size_t)row0 * 64);
    const int nf4 = rows * 16;  // float4 elements in this tile
    #pragma unroll
    for (int j = 0; j < 16; ++j) {
        int g = t + j * 256;            // flat float4 index within tile
        if (g < nf4) {
            float4 v = Xv[g];
            int r  = g >> 4;            // row within tile
            int fq = (g & 15) << 2;     // feature offset (multiple of 4)
            float* dst = &tile[r * PAD + fq];
            dst[0] = v.x; dst[1] = v.y; dst[2] = v.z; dst[3] = v.w;
        }
    }
    __syncthreads();

    if (t >= rows) return;

    const float a     = *pa;
    const float inv_b = 1.0f / *pb;
    const float* myrow = &tile[t * PAD];

    float s = 0.0f;
    #pragma unroll
    for (int c = 0; c < 8; ++c) {
        float z = 0.0f;
        #pragma unroll
        for (int d = 0; d < 4; ++d) {
            // leaf_idx / Wc are wave-uniform -> scalar loads, cached
            z += myrow[leaf_idx[c * 4 + d]] * Wc[c * 4 + d];
        }
        float u = (z - a) * inv_b;
        s += __expf(-u * u) * wr[c];
    }
    float u = (s - a) * inv_b;
    out[row0 + t] = __expf(-u * u);
}

extern "C" void kernel_launch(void* const* d_in, const int* in_sizes, int n_in,
                              void* d_out, int out_size, void* d_ws, size_t ws_size,
                              hipStream_t stream)
{
    const float* X  = (const float*)d_in[0];
    const int*   li = (const int*)  d_in[1];
    const float* Wc = (const float*)d_in[2];
    const float* wr = (const float*)d_in[3];
    const float* pa = (const float*)d_in[4];
    const float* pb = (const float*)d_in[5];
    float* out = (float*)d_out;

    const int n    = out_size;              // N rows (output is (N,1) f32)
    const int grid = (n + TILE - 1) / TILE; // 4096 blocks for N=1M

    flextree_kernel<<<grid, 256, 0, stream>>>(X, li, Wc, wr, pa, pb, out, n);
}

// Round 3
// 47.659 us; speedup vs baseline: 1.3617x; 1.3617x over previous
//
#include <hip/hip_runtime.h>

// FlexTree: y = g(h @ w_root), h[c] = g(sum_d X[n, leaf_idx[c,d]] * W_child[c,d]),
// g(x) = exp(-((x-a)/b)^2).  N=1048576, F=64, C=8, D=4.
// Memory-bound: 256 MB read + 4 MB write -> ~41 us floor at 6.3 TB/s.
//
// Structure: one WAVE per 64-row tile (no __syncthreads anywhere; single-wave
// LDS ops are in-order so ds_write->ds_read hazards are covered by lgkmcnt).
// 64-thread blocks, 16.6 KB LDS each -> 8 waves/CU. Each block owns 8
// consecutive tiles (grid covers N exactly, no tail imbalance) and
// double-buffers the next tile's loads in registers while computing.

#define TPB 8     // tiles per block
#define PAD 65    // row stride in LDS floats; (t + idx) mod 32 -> 2-way = free

typedef float f4 __attribute__((ext_vector_type(4)));  // nontemporal-compatible

__global__ __launch_bounds__(64) void flextree_kernel(
    const float* __restrict__ X,
    const int*   __restrict__ leaf_idx,   // [8*4]
    const float* __restrict__ Wc,         // [8*4]
    const float* __restrict__ wr,         // [8]
    const float* __restrict__ pa,
    const float* __restrict__ pb,
    float* __restrict__ out,
    int n)
{
    __shared__ float lds[64 * PAD];
    const int t = threadIdx.x;              // 0..63
    const int tile0 = blockIdx.x * TPB;
    const int ntiles = (n + 63) >> 6;

    // ---- hoist the tiny uniform params (scalar-cached, reused across 8 tiles)
    const float a     = *pa;
    const float inv_b = 1.0f / *pb;
    int   li[32]; float w[32]; float wroot[8];
    #pragma unroll
    for (int k = 0; k < 32; ++k) { li[k] = leaf_idx[k]; w[k] = Wc[k]; }
    #pragma unroll
    for (int c = 0; c < 8; ++c) wroot[c] = wr[c];

    const f4* Xv = reinterpret_cast<const f4*>(X);
    const int max_f4 = n * 16 - 1;          // clamp for (impossible here) partial tiles

    // lane g = t + 64*j walks 1 KB contiguous per instruction: coalesced.
    auto load_tile = [&](int tile, f4* v) {
        int base = tile * 1024 + t;
        #pragma unroll
        for (int j = 0; j < 16; ++j) {
            int g = base + j * 64;
            v[j] = __builtin_nontemporal_load(&Xv[g <= max_f4 ? g : max_f4]);
        }
    };

    // write bank = (th + 4*tl + k) mod 32 over 64 lanes: exact 2-way -> free
    auto write_tile = [&](const f4* v) {
        #pragma unroll
        for (int j = 0; j < 16; ++j) {
            int g  = t + j * 64;
            int r  = g >> 4;
            int fq = (g & 15) << 2;
            float* dst = &lds[r * PAD + fq];
            dst[0] = v[j].x; dst[1] = v[j].y; dst[2] = v[j].z; dst[3] = v[j].w;
        }
    };

    auto compute_tile = [&](int tile) {
        const float* myrow = &lds[t * PAD];
        float s = 0.0f;
        #pragma unroll
        for (int c = 0; c < 8; ++c) {
            float z = 0.0f;
            #pragma unroll
            for (int d = 0; d < 4; ++d)
                z = fmaf(myrow[li[c * 4 + d]], w[c * 4 + d], z);
            float u = (z - a) * inv_b;
            s = fmaf(__expf(-u * u), wroot[c], s);
        }
        float u = (s - a) * inv_b;
        int row = tile * 64 + t;
        if (row < n) __builtin_nontemporal_store(__expf(-u * u), &out[row]);
    };

    f4 va[16], vb[16];
    if (tile0 >= ntiles) return;
    load_tile(tile0, va);

    #pragma unroll
    for (int i = 0; i < TPB; i += 2) {
        // -- tile i (in va)
        write_tile(va);                                   // waits va's vmcnt
        if (tile0 + i + 1 < ntiles) load_tile(tile0 + i + 1, vb);  // prefetch
        compute_tile(tile0 + i);                          // overlaps vb's loads
        // -- tile i+1 (in vb)
        if (tile0 + i + 1 < ntiles) {
            write_tile(vb);
            if (tile0 + i + 2 < ntiles) load_tile(tile0 + i + 2, va);
            compute_tile(tile0 + i + 1);
        }
        if (tile0 + i + 2 >= ntiles) break;
    }
}

extern "C" void kernel_launch(void* const* d_in, const int* in_sizes, int n_in,
                              void* d_out, int out_size, void* d_ws, size_t ws_size,
                              hipStream_t stream)
{
    const float* X  = (const float*)d_in[0];
    const int*   li = (const int*)  d_in[1];
    const float* Wc = (const float*)d_in[2];
    const float* wr = (const float*)d_in[3];
    const float* pa = (const float*)d_in[4];
    const float* pb = (const float*)d_in[5];
    float* out = (float*)d_out;

    const int n      = out_size;                 // N rows
    const int ntiles = (n + 63) >> 6;            // 16384
    const int grid   = (ntiles + TPB - 1) / TPB; // 2048 blocks x 64 thr, 8 tiles each

    flextree_kernel<<<grid, 64, 0, stream>>>(X, li, Wc, wr, pa, pb, out, n);
}

// Round 4
// 45.429 us; speedup vs baseline: 1.4286x; 1.0491x over previous
//
#include <hip/hip_runtime.h>

// FlexTree: y = g(h @ w_root), h[c] = g(sum_d X[n, leaf_idx[c,d]] * W_child[c,d]),
// g(x) = exp(-((x-a)/b)^2).  N=1048576, F=64, C=8, D=4.
// Memory-bound: 256 MB read + 4 MB write. Measured r3: 47.66 us, 2M LDS write
// conflicts, FETCH 131MB (L3 serves ~half of X across replays).
//
// r4 changes: (1) permuted lane->chunk mapping so ds_write banks = (4j+l+k)%32
// -> zero conflicts (was 2-way per half-wave = 2M cycles); (2) plain (non-NT)
// loads so X stays Infinity-Cache resident; (3) uniform tables in SGPRs via
// readfirstlane + loop-invariant LDS byte addresses precomputed once.

#define TPB 8     // tiles per block (grid covers N exactly: 2048 * 8 * 64 = 1M)
#define PAD 65    // LDS row stride; read bank = (t + idx) % 32 -> 2-way = free

typedef float f4 __attribute__((ext_vector_type(4)));

__device__ __forceinline__ float rfl_f(float x) {
    return __int_as_float(__builtin_amdgcn_readfirstlane(__float_as_int(x)));
}

__global__ __launch_bounds__(64) void flextree_kernel(
    const float* __restrict__ X,
    const int*   __restrict__ leaf_idx,   // [8*4]
    const float* __restrict__ Wc,         // [8*4]
    const float* __restrict__ wr,         // [8]
    const float* __restrict__ pa,
    const float* __restrict__ pb,
    float* __restrict__ out,
    int n)
{
    __shared__ float lds[64 * PAD];
    const int t = threadIdx.x;              // 0..63
    const int tile0 = blockIdx.x * TPB;
    const int ntiles = (n + 63) >> 6;
    if (tile0 >= ntiles) return;

    // ---- wave-uniform params -> SGPRs (live across all 8 tiles) ----
    const float a     = rfl_f(*pa);
    const float inv_b = rfl_f(1.0f / *pb);
    float w[32]; float wroot[8]; int ba[32];
    #pragma unroll
    for (int k = 0; k < 32; ++k) {
        int idx = __builtin_amdgcn_readfirstlane(leaf_idx[k]);
        w[k]  = rfl_f(Wc[k]);
        ba[k] = (t * PAD + idx) * 4;        // per-thread LDS byte addr, loop-invariant
    }
    #pragma unroll
    for (int c = 0; c < 8; ++c) wroot[c] = rfl_f(wr[c]);

    const f4* Xv = reinterpret_cast<const f4*>(X);
    const int max_f4 = n * 16 - 1;
    // permuted slot within each contiguous 1KB chunk: same address SET per
    // instruction (full coalescing), but lane l owns row 4j+(l&3), chunk l>>2.
    const int slot   = 16 * (t & 3) + (t >> 2);
    const int wbase  = (t & 3) * PAD + (t >> 2) * 4;   // dword offset for j=0

    auto load_tile = [&](int tile, f4* v) {
        int base = tile * 1024 + slot;
        #pragma unroll
        for (int j = 0; j < 16; ++j) {
            int g = base + j * 64;
            v[j] = Xv[g <= max_f4 ? g : max_f4];
        }
    };

    // bank = (wbase + 4j*PAD + k) % 32 = ((t&3) + 4*(t>>2) + 4j + k) % 32
    //      = (t + 4j + k) % 32 -> each 32-lane half covers all 32 banks once.
    auto write_tile = [&](const f4* v) {
        #pragma unroll
        for (int j = 0; j < 16; ++j) {
            float* dst = &lds[wbase + j * 4 * PAD];
            dst[0] = v[j].x; dst[1] = v[j].y; dst[2] = v[j].z; dst[3] = v[j].w;
        }
    };

    const char* ldsb = (const char*)lds;
    auto compute_tile = [&](int tile) {
        float s = 0.0f;
        #pragma unroll
        for (int c = 0; c < 8; ++c) {
            float z = 0.0f;
            #pragma unroll
            for (int d = 0; d < 4; ++d)
                z = fmaf(*(const float*)(ldsb + ba[c * 4 + d]), w[c * 4 + d], z);
            float u = (z - a) * inv_b;
            s = fmaf(__expf(-u * u), wroot[c], s);
        }
        float u = (s - a) * inv_b;
        int row = tile * 64 + t;
        if (row < n) __builtin_nontemporal_store(__expf(-u * u), &out[row]);
    };

    f4 va[16], vb[16];
    load_tile(tile0, va);

    #pragma unroll
    for (int i = 0; i < TPB; i += 2) {
        write_tile(va);                                            // waits va
        if (tile0 + i + 1 < ntiles) load_tile(tile0 + i + 1, vb);  // prefetch
        compute_tile(tile0 + i);                                   // overlaps vb
        if (tile0 + i + 1 < ntiles) {
            write_tile(vb);
            if (tile0 + i + 2 < ntiles) load_tile(tile0 + i + 2, va);
            compute_tile(tile0 + i + 1);
        }
        if (tile0 + i + 2 >= ntiles) break;
    }
}

extern "C" void kernel_launch(void* const* d_in, const int* in_sizes, int n_in,
                              void* d_out, int out_size, void* d_ws, size_t ws_size,
                              hipStream_t stream)
{
    const float* X  = (const float*)d_in[0];
    const int*   li = (const int*)  d_in[1];
    const float* Wc = (const float*)d_in[2];
    const float* wr = (const float*)d_in[3];
    const float* pa = (const float*)d_in[4];
    const float* pb = (const float*)d_in[5];
    float* out = (float*)d_out;

    const int n      = out_size;                 // N rows
    const int ntiles = (n + 63) >> 6;            // 16384
    const int grid   = (ntiles + TPB - 1) / TPB; // 2048 blocks x 64 thr, 8 tiles each

    flextree_kernel<<<grid, 64, 0, stream>>>(X, li, Wc, wr, pa, pb, out, n);
}